// Round 1
// baseline (21.388 us; speedup 1.0000x reference)
//
#include <hip/hip_runtime.h>
#include <math.h>

#define NCLUST 16
#define MAIN_BLOCKS 1024
#define MAIN_THREADS 256

// Pass 1: stream X, compute g(x)^2 partial sums per block (deterministic).
__global__ __launch_bounds__(MAIN_THREADS) void gmm_main_kernel(
    const float* __restrict__ X,
    const float* __restrict__ means,
    const float* __restrict__ chols,
    const float* __restrict__ weights,
    double* __restrict__ partials,
    int nvec)
{
    __shared__ float par[NCLUST][8];
    const int tid = threadIdx.x;
    if (tid < NCLUST) {
        const int k = tid;
        // chols layout [K,2,2] row-major; tril -> L00, L10, L11
        const float c00 = chols[4*k + 0];
        const float c10 = chols[4*k + 2];
        const float c11 = chols[4*k + 3];
        // S = L L^T
        const float s11 = c00*c00;
        const float s12 = c00*c10;
        const float s22 = c10*c10 + c11*c11;
        const float det = s11*s22 - s12*s12;
        const float invdet = 1.0f / det;
        const float KC = -0.7213475204444817f;   // -0.5 * log2(e)
        // maha quadratic form coeffs, scaled so exp(-0.5 m) = 2^(A dx^2 + B dxdy + C dy^2)
        const float A = KC * s22 * invdet;
        const float B = KC * (-2.0f * s12) * invdet;
        const float C = KC * s11 * invdet;
        const float mx = means[2*k + 0];
        const float my = means[2*k + 1];
        const float coef = weights[k] / (6.283185307179586f * sqrtf(det));
        // expand around mean: t(x,y) = A x^2 + B xy + C y^2 + D x + E y + F
        const float D = -(2.0f*A*mx + B*my);
        const float E = -(2.0f*C*my + B*mx);
        const float F = A*mx*mx + B*mx*my + C*my*my + log2f(fabsf(coef));
        par[k][0] = A;  par[k][1] = B;  par[k][2] = C;
        par[k][3] = D;  par[k][4] = E;  par[k][5] = F;
        par[k][6] = (coef < 0.0f) ? -1.0f : 1.0f;
    }
    __syncthreads();

    // hoist params into registers (all statically indexed after unroll)
    float a[NCLUST], b[NCLUST], c[NCLUST], d[NCLUST], e[NCLUST], f[NCLUST], sg[NCLUST];
    #pragma unroll
    for (int k = 0; k < NCLUST; ++k) {
        a[k] = par[k][0]; b[k] = par[k][1]; c[k] = par[k][2];
        d[k] = par[k][3]; e[k] = par[k][4]; f[k] = par[k][5];
        sg[k] = par[k][6];
    }

    const float4* __restrict__ X4 = (const float4*)X;
    float acc = 0.0f;
    const int stride = MAIN_BLOCKS * MAIN_THREADS;
    for (int i = blockIdx.x * MAIN_THREADS + tid; i < nvec; i += stride) {
        const float4 v = X4[i];   // two samples: (v.x,v.y), (v.z,v.w)
        const float xx0 = v.x*v.x, xy0 = v.x*v.y, yy0 = v.y*v.y;
        const float xx1 = v.z*v.z, xy1 = v.z*v.w, yy1 = v.w*v.w;
        float g0 = 0.0f, g1 = 0.0f;
        #pragma unroll
        for (int k = 0; k < NCLUST; ++k) {
            float t0 = fmaf(a[k], xx0,
                       fmaf(b[k], xy0,
                       fmaf(c[k], yy0,
                       fmaf(d[k], v.x,
                       fmaf(e[k], v.y, f[k])))));
            g0 = fmaf(sg[k], exp2f(t0), g0);
            float t1 = fmaf(a[k], xx1,
                       fmaf(b[k], xy1,
                       fmaf(c[k], yy1,
                       fmaf(d[k], v.z,
                       fmaf(e[k], v.w, f[k])))));
            g1 = fmaf(sg[k], exp2f(t1), g1);
        }
        acc = fmaf(g0, g0, acc);
        acc = fmaf(g1, g1, acc);
    }

    // wave (64-lane) reduction, then cross-wave via LDS
    #pragma unroll
    for (int off = 32; off > 0; off >>= 1)
        acc += __shfl_down(acc, off, 64);
    __shared__ float wsum[MAIN_THREADS / 64];
    if ((tid & 63) == 0) wsum[tid >> 6] = acc;
    __syncthreads();
    if (tid == 0) {
        float s = 0.0f;
        #pragma unroll
        for (int w = 0; w < MAIN_THREADS / 64; ++w) s += wsum[w];
        partials[blockIdx.x] = (double)s;
    }
}

// Pass 2: compute z (16x16 pair normalizer), reduce block partials, final scalar.
__global__ __launch_bounds__(256) void gmm_final_kernel(
    const float* __restrict__ means,
    const float* __restrict__ chols,
    const float* __restrict__ weights,
    const double* __restrict__ partials,
    float* __restrict__ out,
    int nblocks,
    int nsamples)
{
    const int tid = threadIdx.x;
    __shared__ float s11s[NCLUST], s12s[NCLUST], s22s[NCLUST];
    __shared__ float wv[NCLUST], mxs[NCLUST], mys[NCLUST];
    if (tid < NCLUST) {
        const float c00 = chols[4*tid + 0];
        const float c10 = chols[4*tid + 2];
        const float c11 = chols[4*tid + 3];
        s11s[tid] = c00*c00;
        s12s[tid] = c00*c10;
        s22s[tid] = c10*c10 + c11*c11;
        wv[tid]  = weights[tid];
        mxs[tid] = means[2*tid + 0];
        mys[tid] = means[2*tid + 1];
    }
    __syncthreads();

    // one (i,j) cluster pair per thread
    const int i = tid >> 4, j = tid & 15;
    const float t11 = s11s[i] + s11s[j];
    const float t12 = s12s[i] + s12s[j];
    const float t22 = s22s[i] + s22s[j];
    const float det = t11*t22 - t12*t12;
    const float mdx = mxs[i] - mxs[j];
    const float mdy = mys[i] - mys[j];
    const float m2 = (t22*mdx*mdx - 2.0f*t12*mdx*mdy + t11*mdy*mdy) / det;
    const float Zij = expf(-0.5f * m2) / (6.283185307179586f * sqrtf(det));
    double zc = (double)(wv[i] * wv[j] * Zij);

    // sum the per-block g^2 partials
    double ps = 0.0;
    for (int bi = tid; bi < nblocks; bi += 256) ps += partials[bi];

    __shared__ double red[256], red2[256];
    red[tid] = ps;
    red2[tid] = zc;
    __syncthreads();
    for (int s = 128; s > 0; s >>= 1) {
        if (tid < s) { red[tid] += red[tid + s]; red2[tid] += red2[tid + s]; }
        __syncthreads();
    }
    if (tid == 0) {
        const double total = red[0];   // sum_n g(x_n)^2
        const double z = red2[0];      // pair normalizer
        out[0] = (float)(-(log(total) - log(z)) / (double)nsamples);
    }
}

extern "C" void kernel_launch(void* const* d_in, const int* in_sizes, int n_in,
                              void* d_out, int out_size, void* d_ws, size_t ws_size,
                              hipStream_t stream)
{
    const float* X       = (const float*)d_in[0];
    const float* means   = (const float*)d_in[1];
    const float* chols   = (const float*)d_in[2];
    const float* weights = (const float*)d_in[3];
    float* out = (float*)d_out;
    double* partials = (double*)d_ws;   // MAIN_BLOCKS doubles

    const int nsamples = in_sizes[0] / 2;   // X is [N,2]
    const int nvec = nsamples / 2;          // float4 = 2 samples

    gmm_main_kernel<<<MAIN_BLOCKS, MAIN_THREADS, 0, stream>>>(
        X, means, chols, weights, partials, nvec);
    gmm_final_kernel<<<1, 256, 0, stream>>>(
        means, chols, weights, partials, out, MAIN_BLOCKS, nsamples);
}